// Round 10
// baseline (899.335 us; speedup 1.0000x reference)
//
#include <hip/hip_runtime.h>

#define T_LEN 2048
#define HID 64
#define EMB 128
#define WD 16                // steps per window (barrier period) — R25: 8->16
#define NWIN (T_LEN / WD)    // 128
#define NPH (NWIN + 4)       // +4 windows of pipeline lag (C2)

typedef _Float16 half2_t __attribute__((ext_vector_type(2)));
typedef unsigned uint4v __attribute__((ext_vector_type(4)));

#if __has_builtin(__builtin_amdgcn_exp2f)
#define EXP2F(x) __builtin_amdgcn_exp2f(x)
#else
#define EXP2F(x) exp2f(x)
#endif
#if __has_builtin(__builtin_amdgcn_rcpf)
#define RCPF(x) __builtin_amdgcn_rcpf(x)
#else
#define RCPF(x) (1.0f / (x))
#endif

#define LOG2E 1.4426950408889634f
#define MAGIC 12582912.f           // 1.5 * 2^23: RNE integer rounding
#define MAGIC_I 0x4B400000

// Recurrent i8 dot fed from SGPR-resident packed h (R23-verified).
__device__ __forceinline__ float dot64_i8s(const uint4v* wq, const int* hs,
                                           float fs, float ext) {
    int a0 = 0, a1 = 0, a2 = 0, a3 = 0;
    #pragma unroll
    for (int q = 0; q < 4; ++q) {
        a0 = __builtin_amdgcn_sdot4((int)wq[q][0], hs[4 * q + 0], a0, false);
        a1 = __builtin_amdgcn_sdot4((int)wq[q][1], hs[4 * q + 1], a1, false);
        a2 = __builtin_amdgcn_sdot4((int)wq[q][2], hs[4 * q + 2], a2, false);
        a3 = __builtin_amdgcn_sdot4((int)wq[q][3], hs[4 * q + 3], a3, false);
    }
    int s = (a0 + a1) + (a2 + a3);
    return fmaf((float)s, fs, ext);
}

// Producer i8 dot: weights (per-lane row) vs wave-uniform h quads from LDS.
__device__ __forceinline__ float dot64_i8v(const uint4v* wq, const uint4v* g,
                                           float fs) {
    int a0 = 0, a1 = 0, a2 = 0, a3 = 0;
    #pragma unroll
    for (int q = 0; q < 4; ++q) {
        a0 = __builtin_amdgcn_sdot4((int)wq[q][0], (int)g[q][0], a0, false);
        a1 = __builtin_amdgcn_sdot4((int)wq[q][1], (int)g[q][1], a1, false);
        a2 = __builtin_amdgcn_sdot4((int)wq[q][2], (int)g[q][2], a2, false);
        a3 = __builtin_amdgcn_sdot4((int)wq[q][3], (int)g[q][3], a3, false);
    }
    int s = (a0 + a1) + (a2 + a3);
    return (float)s * fs;
}

// In-register h broadcast (R23-verified): lane L contributes byte qb at slot
// L&3; 2 DPP quad-perm ORs assemble the packed dword in every lane of each
// quad; 16 readlanes lift h to SGPRs. quad_perm(1,0,3,2)=0xB1; (2,3,0,1)=0x4E.
__device__ __forceinline__ void pack_hq(int qb, int lane, int* hs) {
    int qv = (qb & 0xff) << (8 * (lane & 3));
    qv |= __builtin_amdgcn_update_dpp(0, qv, 0xB1, 0xf, 0xf, false);
    qv |= __builtin_amdgcn_update_dpp(0, qv, 0x4E, 0xf, 0xf, false);
    #pragma unroll
    for (int k = 0; k < 16; ++k) hs[k] = __builtin_amdgcn_readlane(qv, 4 * k);
}

__device__ __forceinline__ unsigned pack4i8(float4 v, float s) {
    int q0 = (int)rintf(v.x * s), q1 = (int)rintf(v.y * s);
    int q2 = (int)rintf(v.z * s), q3 = (int)rintf(v.w * s);
    return (unsigned)((q0 & 0xff) | ((q1 & 0xff) << 8) |
                      ((q2 & 0xff) << 16) | ((q3 & 0xff) << 24));
}

// Quantize one 64-float weight row to i8, dynamic scale 127/max|row|.
__device__ __forceinline__ float quant_row(const float* __restrict__ Wp, uint4v* dst) {
    const float4* p = reinterpret_cast<const float4*>(Wp);
    float m = 1e-8f;
    #pragma unroll
    for (int k = 0; k < 16; ++k) {
        float4 v = p[k];
        m = fmaxf(m, fmaxf(fmaxf(fabsf(v.x), fabsf(v.y)),
                           fmaxf(fabsf(v.z), fabsf(v.w))));
    }
    const float s = 127.f / m;
    #pragma unroll
    for (int k = 0; k < 4; ++k) {
        uint4v q;
        q[0] = pack4i8(p[4 * k + 0], s);
        q[1] = pack4i8(p[4 * k + 1], s);
        q[2] = pack4i8(p[4 * k + 2], s);
        q[3] = pack4i8(p[4 * k + 3], s);
        dst[k] = q;
    }
    return m;
}

// ROUND 25 = R24 (878.6us, WIN -7.4%) micro-bundle. R24 post-mortem: wall
// ~1014 cyc/step = i8 dot issue ~256 + gates/pack ~180 + SERIAL TAIL
// latency ~300-400 (single wave/SIMD, no bubble-filler — intrinsic after
// R17/18/19 falsified all cross-wave hiding) + barrier ~12. R25 attacks the
// two open pools: (1) WD 8->16 halves barrier count (260->132 phases);
// (2) tail trim: ao127 pre-scaled off-path (parallel to cst/tanh chain) +
// magic-constant RNE quantization (fmaf+bitsub replaces mul+rint+cvt),
// ~3 dependent ops off the chain; (3) 16-step unroll gives the compiler
// more load-hoisting room (VGPR headroom to 256 at 2 waves/EU).
// PRE-COMMIT: if >=865us, remaining wall = irreducible chain latency;
// declare structural ceiling.
// Ledger: R16 neutral; R17 CU-halving dead; R18 cross-CU dead; R19
// per-step barrier dead; R20 pk_fma same-rate; R21 setprio null; R22 i8
// -2.6%; R23 SGPR-chain null; R24 i8-producers+evacuation -7.4%.
__global__ __launch_bounds__(512)
__attribute__((amdgpu_waves_per_eu(2, 2)))
void lstm3_fused(
    const float* __restrict__ x,
    const float* __restrict__ Wih0, const float* __restrict__ Whh0,
    const float* __restrict__ bih0, const float* __restrict__ bhh0,
    const float* __restrict__ Wih1, const float* __restrict__ Whh1,
    const float* __restrict__ bih1, const float* __restrict__ bhh1,
    const float* __restrict__ Wih2, const float* __restrict__ Whh2,
    const float* __restrict__ bih2, const float* __restrict__ bhh2,
    const float* __restrict__ fcW,  const float* __restrict__ fcb,
    float* __restrict__ out)
{
    const int b   = blockIdx.x;
    const int tid = threadIdx.x;
    const int wv  = tid >> 6;          // 0..7 (wave-uniform role)
    const int L   = tid & 63;          // owned h-index / row-lane

    __shared__ __align__(16) signed char h0q[2 * WD][HID];   // i8 producer feed
    __shared__ __align__(16) signed char h1q[2 * WD][HID];
    __shared__ __align__(16) _Float16 h2ring[2][HID];        // f16 FC feed
    __shared__ float p1buf[2][WD][4][HID];                   // wih1 partials
    __shared__ float p2buf[2][WD][4][HID];                   // wih2 partials
    __shared__ __align__(16) float xs[T_LEN];

    // Stage x[b,0,:]; zero the rings.
    {
        const float4* xg4 = reinterpret_cast<const float4*>(x + b * T_LEN);
        reinterpret_cast<float4*>(xs)[tid] = xg4[tid];
        reinterpret_cast<unsigned*>(h0q)[tid] = 0u;   // 512 dwords each
        reinterpret_cast<unsigned*>(h1q)[tid] = 0u;
        if (tid < 64) reinterpret_cast<unsigned*>(h2ring)[tid] = 0u;
    }

    const float sI = -LOG2E, sF = -LOG2E, sG = -2.f * LOG2E, sO = -LOG2E;
    const float scl[4] = {sI, sF, sG, sO};

    uint4v wq[4][4];                   // i8 rows: C = whh; producers = wih
    float bias4[4] = {0.f, 0.f, 0.f, 0.f};
    float wx4[4]   = {0.f, 0.f, 0.f, 0.f};
    float fs4[4]   = {0.f, 0.f, 0.f, 0.f};

    if (wv < 3) {                      // C_l: whh_l all 4 gate rows, i8
        const float* Wh = (wv == 0) ? Whh0 : (wv == 1) ? Whh1 : Whh2;
        const float* bi = (wv == 0) ? bih0 : (wv == 1) ? bih1 : bih2;
        const float* bh = (wv == 0) ? bhh0 : (wv == 1) ? bhh1 : bhh2;
        #pragma unroll
        for (int c = 0; c < 4; ++c) {
            float m = quant_row(Wh + (c * 64 + L) * 64, wq[c]);
            fs4[c] = scl[c] * m * (1.f / (127.f * 127.f));
            bias4[c] = (bi[c * 64 + L] + bh[c * 64 + L]) * scl[c];
        }
        if (wv == 0) {
            #pragma unroll
            for (int c = 0; c < 4; ++c) wx4[c] = Wih0[c * 64 + L] * scl[c];
        }
    } else if (wv == 3 || wv == 7) {   // producer: full Wih_l, 4 rows/lane, i8
        const float* Wsrc = (wv == 3) ? Wih1 : Wih2;
        #pragma unroll
        for (int c = 0; c < 4; ++c) {
            float m = quant_row(Wsrc + (c * 64 + L) * 64, wq[c]);
            fs4[c] = scl[c] * m * (1.f / (127.f * 127.f));
        }
    }
    // wv 4,5,6: idle (barrier participants only).

    float cst = 0.f;                   // cell state (C waves, lane-local)
    int hs[16];                        // packed i8 h[t-1], wave-uniform
    #pragma unroll
    for (int k = 0; k < 16; ++k) hs[k] = 0;

    __syncthreads();

    for (int ph = 0; ph < NPH; ++ph) {
        const int par = ph & 1;

        if (wv == 0) {
            if (ph < NWIN) {           // h0 window ph
                const int tb = ph * WD;
                #pragma unroll
                for (int j = 0; j < WD; ++j) {
                    const int r = par * WD + j;
                    float xv = xs[tb + j];
                    float d0 = dot64_i8s(wq[0], hs, fs4[0], fmaf(wx4[0], xv, bias4[0]));
                    float d1 = dot64_i8s(wq[1], hs, fs4[1], fmaf(wx4[1], xv, bias4[1]));
                    float d2 = dot64_i8s(wq[2], hs, fs4[2], fmaf(wx4[2], xv, bias4[2]));
                    float d3 = dot64_i8s(wq[3], hs, fs4[3], fmaf(wx4[3], xv, bias4[3]));
                    float ai = RCPF(1.f + EXP2F(d0));
                    float af = RCPF(1.f + EXP2F(d1));
                    float ag = fmaf(2.f, RCPF(1.f + EXP2F(d2)), -1.f);
                    float ao127 = 127.f * RCPF(1.f + EXP2F(d3));   // off-path
                    cst = fmaf(af, cst, ai * ag);
                    float tc = fmaf(2.f, RCPF(1.f + EXP2F(-2.f * LOG2E * cst)), -1.f);
                    float qf = fmaf(ao127, tc, MAGIC);             // RNE round
                    int qb = __builtin_bit_cast(int, qf) - MAGIC_I;
                    h0q[r][L] = (signed char)qb;       // producer feed
                    pack_hq(qb, L, hs);                // chain: regs only
                }
            }
        } else if (wv == 1) {
            if (ph >= 2 && ph < NWIN + 2) {    // h1 window ph-2 (p1[par] ready)
                const float (*pb)[4][HID] = p1buf[par];
                #pragma unroll
                for (int j = 0; j < WD; ++j) {
                    const int r = par * WD + j;
                    float d0 = dot64_i8s(wq[0], hs, fs4[0], bias4[0] + pb[j][0][L]);
                    float d1 = dot64_i8s(wq[1], hs, fs4[1], bias4[1] + pb[j][1][L]);
                    float d2 = dot64_i8s(wq[2], hs, fs4[2], bias4[2] + pb[j][2][L]);
                    float d3 = dot64_i8s(wq[3], hs, fs4[3], bias4[3] + pb[j][3][L]);
                    float ai = RCPF(1.f + EXP2F(d0));
                    float af = RCPF(1.f + EXP2F(d1));
                    float ag = fmaf(2.f, RCPF(1.f + EXP2F(d2)), -1.f);
                    float ao127 = 127.f * RCPF(1.f + EXP2F(d3));
                    cst = fmaf(af, cst, ai * ag);
                    float tc = fmaf(2.f, RCPF(1.f + EXP2F(-2.f * LOG2E * cst)), -1.f);
                    float qf = fmaf(ao127, tc, MAGIC);
                    int qb = __builtin_bit_cast(int, qf) - MAGIC_I;
                    h1q[r][L] = (signed char)qb;
                    pack_hq(qb, L, hs);
                }
            }
        } else if (wv == 2) {
            if (ph >= 4) {                     // h2 window ph-4 (p2[par] ready)
                const float (*pb)[4][HID] = p2buf[par];
                #pragma unroll
                for (int j = 0; j < WD; ++j) {
                    float d0 = dot64_i8s(wq[0], hs, fs4[0], bias4[0] + pb[j][0][L]);
                    float d1 = dot64_i8s(wq[1], hs, fs4[1], bias4[1] + pb[j][1][L]);
                    float d2 = dot64_i8s(wq[2], hs, fs4[2], bias4[2] + pb[j][2][L]);
                    float d3 = dot64_i8s(wq[3], hs, fs4[3], bias4[3] + pb[j][3][L]);
                    float ai = RCPF(1.f + EXP2F(d0));
                    float af = RCPF(1.f + EXP2F(d1));
                    float ag = fmaf(2.f, RCPF(1.f + EXP2F(d2)), -1.f);
                    float ao = RCPF(1.f + EXP2F(d3));
                    cst = fmaf(af, cst, ai * ag);
                    float tc = fmaf(2.f, RCPF(1.f + EXP2F(-2.f * LOG2E * cst)), -1.f);
                    float hf = ao * tc;
                    h2ring[j & 1][L] = (_Float16)hf;   // FC feed (f16 of true h)
                    float qf = fmaf(hf, 127.f, MAGIC);
                    int qb = __builtin_bit_cast(int, qf) - MAGIC_I;
                    pack_hq(qb, L, hs);
                }
            }
        } else if (wv == 3) {
            if (ph >= 1 && ph < NWIN + 1) {    // p1: Wih1 x h0 window ph-1
                float (*po)[4][HID] = p1buf[par ^ 1];
                const signed char* hw = &h0q[(par ^ 1) * WD][0];
                #pragma unroll
                for (int j = 0; j < WD; ++j) {
                    const uint4v* g = reinterpret_cast<const uint4v*>(hw + j * HID);
                    uint4v gq[4] = {g[0], g[1], g[2], g[3]};   // wave-uniform
                    po[j][0][L] = dot64_i8v(wq[0], gq, fs4[0]);
                    po[j][1][L] = dot64_i8v(wq[1], gq, fs4[1]);
                    po[j][2][L] = dot64_i8v(wq[2], gq, fs4[2]);
                    po[j][3][L] = dot64_i8v(wq[3], gq, fs4[3]);
                }
            }
        } else if (wv == 7) {
            if (ph >= 3 && ph < NWIN + 3) {    // p2: Wih2 x h1 window ph-3
                float (*po)[4][HID] = p2buf[par ^ 1];
                const signed char* hw = &h1q[(par ^ 1) * WD][0];
                #pragma unroll
                for (int j = 0; j < WD; ++j) {
                    const uint4v* g = reinterpret_cast<const uint4v*>(hw + j * HID);
                    uint4v gq[4] = {g[0], g[1], g[2], g[3]};
                    po[j][0][L] = dot64_i8v(wq[0], gq, fs4[0]);
                    po[j][1][L] = dot64_i8v(wq[1], gq, fs4[1]);
                    po[j][2][L] = dot64_i8v(wq[2], gq, fs4[2]);
                    po[j][3][L] = dot64_i8v(wq[3], gq, fs4[3]);
                }
            }
        }
        // wv 4,5,6: nothing — barrier only.

        __syncthreads();   // publish window: h rings + p-buffers
    }

    // Final FC (f32): h2[2047] = window 127 step 15 -> slot 15&1 = 1.
    if (tid < EMB) {
        float acc = fcb[tid];
        const _Float16* hf = &h2ring[1][0];
        const float4* W4 = reinterpret_cast<const float4*>(fcW + tid * HID);
        #pragma unroll
        for (int k = 0; k < 16; ++k) {
            float4 wv4 = W4[k];
            acc = fmaf(wv4.x, (float)hf[4 * k + 0], acc);
            acc = fmaf(wv4.y, (float)hf[4 * k + 1], acc);
            acc = fmaf(wv4.z, (float)hf[4 * k + 2], acc);
            acc = fmaf(wv4.w, (float)hf[4 * k + 3], acc);
        }
        out[b * EMB + tid] = acc;
    }
}

extern "C" void kernel_launch(void* const* d_in, const int* in_sizes, int n_in,
                              void* d_out, int out_size, void* d_ws, size_t ws_size,
                              hipStream_t stream) {
    const float* x    = (const float*)d_in[0];
    const float* Wih0 = (const float*)d_in[1];
    const float* Whh0 = (const float*)d_in[2];
    const float* bih0 = (const float*)d_in[3];
    const float* bhh0 = (const float*)d_in[4];
    const float* Wih1 = (const float*)d_in[5];
    const float* Whh1 = (const float*)d_in[6];
    const float* bih1 = (const float*)d_in[7];
    const float* bhh1 = (const float*)d_in[8];
    const float* Wih2 = (const float*)d_in[9];
    const float* Whh2 = (const float*)d_in[10];
    const float* bih2 = (const float*)d_in[11];
    const float* bhh2 = (const float*)d_in[12];
    const float* fcW  = (const float*)d_in[13];
    const float* fcb  = (const float*)d_in[14];
    float* out = (float*)d_out;

    lstm3_fused<<<dim3(256), dim3(512), 0, stream>>>(
        x, Wih0, Whh0, bih0, bhh0,
        Wih1, Whh1, bih1, bhh1,
        Wih2, Whh2, bih2, bhh2,
        fcW, fcb, out);
}

// Round 11
// 872.391 us; speedup vs baseline: 1.0309x; 1.0309x over previous
//
#include <hip/hip_runtime.h>

#define T_LEN 2048
#define HID 64
#define EMB 128
#define WD 8                 // steps per window (barrier period) — R26: back to 8
#define NWIN (T_LEN / WD)    // 256
#define NPH (NWIN + 4)       // +4 windows of pipeline lag (C2)

typedef _Float16 half2_t __attribute__((ext_vector_type(2)));
typedef unsigned uint4v __attribute__((ext_vector_type(4)));

#if __has_builtin(__builtin_amdgcn_exp2f)
#define EXP2F(x) __builtin_amdgcn_exp2f(x)
#else
#define EXP2F(x) exp2f(x)
#endif
#if __has_builtin(__builtin_amdgcn_rcpf)
#define RCPF(x) __builtin_amdgcn_rcpf(x)
#else
#define RCPF(x) (1.0f / (x))
#endif

#define LOG2E 1.4426950408889634f
#define MAGIC 12582912.f           // 1.5 * 2^23: RNE integer rounding
#define MAGIC_I 0x4B400000

// Recurrent i8 dot fed from SGPR-resident packed h (R23-verified).
__device__ __forceinline__ float dot64_i8s(const uint4v* wq, const int* hs,
                                           float fs, float ext) {
    int a0 = 0, a1 = 0, a2 = 0, a3 = 0;
    #pragma unroll
    for (int q = 0; q < 4; ++q) {
        a0 = __builtin_amdgcn_sdot4((int)wq[q][0], hs[4 * q + 0], a0, false);
        a1 = __builtin_amdgcn_sdot4((int)wq[q][1], hs[4 * q + 1], a1, false);
        a2 = __builtin_amdgcn_sdot4((int)wq[q][2], hs[4 * q + 2], a2, false);
        a3 = __builtin_amdgcn_sdot4((int)wq[q][3], hs[4 * q + 3], a3, false);
    }
    int s = (a0 + a1) + (a2 + a3);
    return fmaf((float)s, fs, ext);
}

// Producer i8 dot: weights (per-lane row) vs wave-uniform h quads from LDS.
__device__ __forceinline__ float dot64_i8v(const uint4v* wq, const uint4v* g,
                                           float fs) {
    int a0 = 0, a1 = 0, a2 = 0, a3 = 0;
    #pragma unroll
    for (int q = 0; q < 4; ++q) {
        a0 = __builtin_amdgcn_sdot4((int)wq[q][0], (int)g[q][0], a0, false);
        a1 = __builtin_amdgcn_sdot4((int)wq[q][1], (int)g[q][1], a1, false);
        a2 = __builtin_amdgcn_sdot4((int)wq[q][2], (int)g[q][2], a2, false);
        a3 = __builtin_amdgcn_sdot4((int)wq[q][3], (int)g[q][3], a3, false);
    }
    int s = (a0 + a1) + (a2 + a3);
    return (float)s * fs;
}

// In-register h broadcast (R23-verified): lane L contributes byte qb at slot
// L&3; 2 DPP quad-perm ORs assemble the packed dword in every lane of each
// quad; 16 readlanes lift h to SGPRs. quad_perm(1,0,3,2)=0xB1; (2,3,0,1)=0x4E.
__device__ __forceinline__ void pack_hq(int qb, int lane, int* hs) {
    int qv = (qb & 0xff) << (8 * (lane & 3));
    qv |= __builtin_amdgcn_update_dpp(0, qv, 0xB1, 0xf, 0xf, false);
    qv |= __builtin_amdgcn_update_dpp(0, qv, 0x4E, 0xf, 0xf, false);
    #pragma unroll
    for (int k = 0; k < 16; ++k) hs[k] = __builtin_amdgcn_readlane(qv, 4 * k);
}

__device__ __forceinline__ unsigned pack4i8(float4 v, float s) {
    int q0 = (int)rintf(v.x * s), q1 = (int)rintf(v.y * s);
    int q2 = (int)rintf(v.z * s), q3 = (int)rintf(v.w * s);
    return (unsigned)((q0 & 0xff) | ((q1 & 0xff) << 8) |
                      ((q2 & 0xff) << 16) | ((q3 & 0xff) << 24));
}

// Quantize one 64-float weight row to i8, dynamic scale 127/max|row|.
__device__ __forceinline__ float quant_row(const float* __restrict__ Wp, uint4v* dst) {
    const float4* p = reinterpret_cast<const float4*>(Wp);
    float m = 1e-8f;
    #pragma unroll
    for (int k = 0; k < 16; ++k) {
        float4 v = p[k];
        m = fmaxf(m, fmaxf(fmaxf(fabsf(v.x), fabsf(v.y)),
                           fmaxf(fabsf(v.z), fabsf(v.w))));
    }
    const float s = 127.f / m;
    #pragma unroll
    for (int k = 0; k < 4; ++k) {
        uint4v q;
        q[0] = pack4i8(p[4 * k + 0], s);
        q[1] = pack4i8(p[4 * k + 1], s);
        q[2] = pack4i8(p[4 * k + 2], s);
        q[3] = pack4i8(p[4 * k + 3], s);
        dst[k] = q;
    }
    return m;
}

// ROUND 26 = R24 (878.6us, best) + ONLY the tail trim from R25. R25
// post-mortem: WD=16 regressed (899us) — VALUBusy fell 69->67 with a larger
// wall => I-cache thrash from the 2x-unrolled body; the barrier saving
// couldn't compensate. The magic-quant piece was numerically validated
// (absmax 1.953e-3, identical). R26 reverts WD to 8 (exact R24 schedule,
// 43.5KB LDS) and keeps: ao127 pre-scaled OFF the serial chain (runs
// parallel to cst->tanh) + magic-constant RNE quantization (fmaf+bitsub
// replaces mul+rint+cvt+and: ~3 dependent ops off the chain tail).
// PRE-COMMIT: if >=874us (null vs R24), declare structural ceiling —
// remaining wall = single-wave chain latency + i8 dot issue; all
// structural levers measured dead (R16-R25 ledger below).
// Ledger: R16 neutral; R17 CU-halving dead; R18 cross-CU dead; R19
// per-step barrier dead; R20 pk_fma same-rate; R21 setprio null; R22 i8
// -2.6%; R23 SGPR-chain null; R24 i8-producers+evacuation -7.4% WIN;
// R25 WD=16 bundle +2.4% regression (I-cache).
__global__ __launch_bounds__(512)
__attribute__((amdgpu_waves_per_eu(2, 2)))
void lstm3_fused(
    const float* __restrict__ x,
    const float* __restrict__ Wih0, const float* __restrict__ Whh0,
    const float* __restrict__ bih0, const float* __restrict__ bhh0,
    const float* __restrict__ Wih1, const float* __restrict__ Whh1,
    const float* __restrict__ bih1, const float* __restrict__ bhh1,
    const float* __restrict__ Wih2, const float* __restrict__ Whh2,
    const float* __restrict__ bih2, const float* __restrict__ bhh2,
    const float* __restrict__ fcW,  const float* __restrict__ fcb,
    float* __restrict__ out)
{
    const int b   = blockIdx.x;
    const int tid = threadIdx.x;
    const int wv  = tid >> 6;          // 0..7 (wave-uniform role)
    const int L   = tid & 63;          // owned h-index / row-lane

    __shared__ __align__(16) signed char h0q[16][HID];   // i8: producer feed
    __shared__ __align__(16) signed char h1q[16][HID];
    __shared__ __align__(16) _Float16 h2ring[2][HID];    // f16: FC feed
    __shared__ float p1buf[2][WD][4][HID];               // wih1 partials
    __shared__ float p2buf[2][WD][4][HID];               // wih2 partials
    __shared__ __align__(16) float xs[T_LEN];

    // Stage x[b,0,:]; zero the rings.
    {
        const float4* xg4 = reinterpret_cast<const float4*>(x + b * T_LEN);
        reinterpret_cast<float4*>(xs)[tid] = xg4[tid];
        if (tid < 256) {
            reinterpret_cast<unsigned*>(h0q)[tid] = 0u;  // 1024B each
            reinterpret_cast<unsigned*>(h1q)[tid] = 0u;
        }
        if (tid < 64) reinterpret_cast<unsigned*>(h2ring)[tid] = 0u;
    }

    const float sI = -LOG2E, sF = -LOG2E, sG = -2.f * LOG2E, sO = -LOG2E;
    const float scl[4] = {sI, sF, sG, sO};

    uint4v wq[4][4];                   // i8 rows: C = whh; producers = wih
    float bias4[4] = {0.f, 0.f, 0.f, 0.f};
    float wx4[4]   = {0.f, 0.f, 0.f, 0.f};
    float fs4[4]   = {0.f, 0.f, 0.f, 0.f};

    if (wv < 3) {                      // C_l: whh_l all 4 gate rows, i8
        const float* Wh = (wv == 0) ? Whh0 : (wv == 1) ? Whh1 : Whh2;
        const float* bi = (wv == 0) ? bih0 : (wv == 1) ? bih1 : bih2;
        const float* bh = (wv == 0) ? bhh0 : (wv == 1) ? bhh1 : bhh2;
        #pragma unroll
        for (int c = 0; c < 4; ++c) {
            float m = quant_row(Wh + (c * 64 + L) * 64, wq[c]);
            fs4[c] = scl[c] * m * (1.f / (127.f * 127.f));
            bias4[c] = (bi[c * 64 + L] + bh[c * 64 + L]) * scl[c];
        }
        if (wv == 0) {
            #pragma unroll
            for (int c = 0; c < 4; ++c) wx4[c] = Wih0[c * 64 + L] * scl[c];
        }
    } else if (wv == 3 || wv == 7) {   // producer: full Wih_l, 4 rows/lane, i8
        const float* Wsrc = (wv == 3) ? Wih1 : Wih2;
        #pragma unroll
        for (int c = 0; c < 4; ++c) {
            float m = quant_row(Wsrc + (c * 64 + L) * 64, wq[c]);
            fs4[c] = scl[c] * m * (1.f / (127.f * 127.f));
        }
    }
    // wv 4,5,6: idle (barrier participants only).

    float cst = 0.f;                   // cell state (C waves, lane-local)
    int hs[16];                        // packed i8 h[t-1], wave-uniform
    #pragma unroll
    for (int k = 0; k < 16; ++k) hs[k] = 0;

    __syncthreads();

    for (int ph = 0; ph < NPH; ++ph) {
        const int par = ph & 1;

        if (wv == 0) {
            if (ph < NWIN) {           // h0 window ph
                const int tb = ph * WD;
                #pragma unroll
                for (int j = 0; j < WD; ++j) {
                    const int r = par * 8 + j;
                    float xv = xs[tb + j];
                    float d0 = dot64_i8s(wq[0], hs, fs4[0], fmaf(wx4[0], xv, bias4[0]));
                    float d1 = dot64_i8s(wq[1], hs, fs4[1], fmaf(wx4[1], xv, bias4[1]));
                    float d2 = dot64_i8s(wq[2], hs, fs4[2], fmaf(wx4[2], xv, bias4[2]));
                    float d3 = dot64_i8s(wq[3], hs, fs4[3], fmaf(wx4[3], xv, bias4[3]));
                    float ai = RCPF(1.f + EXP2F(d0));
                    float af = RCPF(1.f + EXP2F(d1));
                    float ag = fmaf(2.f, RCPF(1.f + EXP2F(d2)), -1.f);
                    float ao127 = 127.f * RCPF(1.f + EXP2F(d3));   // off-path
                    cst = fmaf(af, cst, ai * ag);
                    float tc = fmaf(2.f, RCPF(1.f + EXP2F(-2.f * LOG2E * cst)), -1.f);
                    float qf = fmaf(ao127, tc, MAGIC);             // RNE round
                    int qb = __builtin_bit_cast(int, qf) - MAGIC_I;
                    h0q[r][L] = (signed char)qb;       // producer feed
                    pack_hq(qb, L, hs);                // chain: regs only
                }
            }
        } else if (wv == 1) {
            if (ph >= 2 && ph < NWIN + 2) {    // h1 window ph-2 (p1[par] ready)
                const float (*pb)[4][HID] = p1buf[par];
                #pragma unroll
                for (int j = 0; j < WD; ++j) {
                    const int r = par * 8 + j;
                    float d0 = dot64_i8s(wq[0], hs, fs4[0], bias4[0] + pb[j][0][L]);
                    float d1 = dot64_i8s(wq[1], hs, fs4[1], bias4[1] + pb[j][1][L]);
                    float d2 = dot64_i8s(wq[2], hs, fs4[2], bias4[2] + pb[j][2][L]);
                    float d3 = dot64_i8s(wq[3], hs, fs4[3], bias4[3] + pb[j][3][L]);
                    float ai = RCPF(1.f + EXP2F(d0));
                    float af = RCPF(1.f + EXP2F(d1));
                    float ag = fmaf(2.f, RCPF(1.f + EXP2F(d2)), -1.f);
                    float ao127 = 127.f * RCPF(1.f + EXP2F(d3));
                    cst = fmaf(af, cst, ai * ag);
                    float tc = fmaf(2.f, RCPF(1.f + EXP2F(-2.f * LOG2E * cst)), -1.f);
                    float qf = fmaf(ao127, tc, MAGIC);
                    int qb = __builtin_bit_cast(int, qf) - MAGIC_I;
                    h1q[r][L] = (signed char)qb;
                    pack_hq(qb, L, hs);
                }
            }
        } else if (wv == 2) {
            if (ph >= 4) {                     // h2 window ph-4 (p2[par] ready)
                const float (*pb)[4][HID] = p2buf[par];
                #pragma unroll
                for (int j = 0; j < WD; ++j) {
                    float d0 = dot64_i8s(wq[0], hs, fs4[0], bias4[0] + pb[j][0][L]);
                    float d1 = dot64_i8s(wq[1], hs, fs4[1], bias4[1] + pb[j][1][L]);
                    float d2 = dot64_i8s(wq[2], hs, fs4[2], bias4[2] + pb[j][2][L]);
                    float d3 = dot64_i8s(wq[3], hs, fs4[3], bias4[3] + pb[j][3][L]);
                    float ai = RCPF(1.f + EXP2F(d0));
                    float af = RCPF(1.f + EXP2F(d1));
                    float ag = fmaf(2.f, RCPF(1.f + EXP2F(d2)), -1.f);
                    float ao = RCPF(1.f + EXP2F(d3));
                    cst = fmaf(af, cst, ai * ag);
                    float tc = fmaf(2.f, RCPF(1.f + EXP2F(-2.f * LOG2E * cst)), -1.f);
                    float hf = ao * tc;
                    h2ring[j & 1][L] = (_Float16)hf;   // FC feed (f16 of true h)
                    float qf = fmaf(hf, 127.f, MAGIC);
                    int qb = __builtin_bit_cast(int, qf) - MAGIC_I;
                    pack_hq(qb, L, hs);
                }
            }
        } else if (wv == 3) {
            if (ph >= 1 && ph < NWIN + 1) {    // p1: Wih1 x h0 window ph-1
                float (*po)[4][HID] = p1buf[par ^ 1];
                const signed char* hw = &h0q[(par ^ 1) * 8][0];
                #pragma unroll
                for (int j = 0; j < WD; ++j) {
                    const uint4v* g = reinterpret_cast<const uint4v*>(hw + j * HID);
                    uint4v gq[4] = {g[0], g[1], g[2], g[3]};   // wave-uniform
                    po[j][0][L] = dot64_i8v(wq[0], gq, fs4[0]);
                    po[j][1][L] = dot64_i8v(wq[1], gq, fs4[1]);
                    po[j][2][L] = dot64_i8v(wq[2], gq, fs4[2]);
                    po[j][3][L] = dot64_i8v(wq[3], gq, fs4[3]);
                }
            }
        } else if (wv == 7) {
            if (ph >= 3 && ph < NWIN + 3) {    // p2: Wih2 x h1 window ph-3
                float (*po)[4][HID] = p2buf[par ^ 1];
                const signed char* hw = &h1q[(par ^ 1) * 8][0];
                #pragma unroll
                for (int j = 0; j < WD; ++j) {
                    const uint4v* g = reinterpret_cast<const uint4v*>(hw + j * HID);
                    uint4v gq[4] = {g[0], g[1], g[2], g[3]};
                    po[j][0][L] = dot64_i8v(wq[0], gq, fs4[0]);
                    po[j][1][L] = dot64_i8v(wq[1], gq, fs4[1]);
                    po[j][2][L] = dot64_i8v(wq[2], gq, fs4[2]);
                    po[j][3][L] = dot64_i8v(wq[3], gq, fs4[3]);
                }
            }
        }
        // wv 4,5,6: nothing — barrier only.

        __syncthreads();   // publish window: h rings + p-buffers
    }

    // Final FC (f32): h2[2047] -> slot 2047&1 = 1.
    if (tid < EMB) {
        float acc = fcb[tid];
        const _Float16* hf = &h2ring[1][0];
        const float4* W4 = reinterpret_cast<const float4*>(fcW + tid * HID);
        #pragma unroll
        for (int k = 0; k < 16; ++k) {
            float4 wv4 = W4[k];
            acc = fmaf(wv4.x, (float)hf[4 * k + 0], acc);
            acc = fmaf(wv4.y, (float)hf[4 * k + 1], acc);
            acc = fmaf(wv4.z, (float)hf[4 * k + 2], acc);
            acc = fmaf(wv4.w, (float)hf[4 * k + 3], acc);
        }
        out[b * EMB + tid] = acc;
    }
}

extern "C" void kernel_launch(void* const* d_in, const int* in_sizes, int n_in,
                              void* d_out, int out_size, void* d_ws, size_t ws_size,
                              hipStream_t stream) {
    const float* x    = (const float*)d_in[0];
    const float* Wih0 = (const float*)d_in[1];
    const float* Whh0 = (const float*)d_in[2];
    const float* bih0 = (const float*)d_in[3];
    const float* bhh0 = (const float*)d_in[4];
    const float* Wih1 = (const float*)d_in[5];
    const float* Whh1 = (const float*)d_in[6];
    const float* bih1 = (const float*)d_in[7];
    const float* bhh1 = (const float*)d_in[8];
    const float* Wih2 = (const float*)d_in[9];
    const float* Whh2 = (const float*)d_in[10];
    const float* bih2 = (const float*)d_in[11];
    const float* bhh2 = (const float*)d_in[12];
    const float* fcW  = (const float*)d_in[13];
    const float* fcb  = (const float*)d_in[14];
    float* out = (float*)d_out;

    lstm3_fused<<<dim3(256), dim3(512), 0, stream>>>(
        x, Wih0, Whh0, bih0, bhh0,
        Wih1, Whh1, bih1, bhh1,
        Wih2, Whh2, bih2, bhh2,
        fcW, fcb, out);
}